// Round 1
// 439.948 us; speedup vs baseline: 1.1582x; 1.1582x over previous
//
#include <hip/hip_runtime.h>
#include <hip/hip_bf16.h>

// Problem: B=8, N=1024, H=2048, L=16
// out[b, tri(i,j), l] = softmax_l( s_proj[b,i,l] + e_proj[b,j,l] + b_span[l] )
// Collapse: A_s = Ws@W_start (16x2048), A_e = We@W_end; proj = x@[A_s;A_e]^T.
// All logits pre-scaled by log2(e) so softmax uses v_exp_f32 (exp2) directly.
// No atomics, no memsets: every workspace buffer is fully written before read.

#define H 2048
#define NSEQ 1024
#define NROWS 8192            // B*N
#define NPAIR 524800          // 1024*1025/2
#define LOG2E 1.4426950408889634f

// ---------------- K0a: transpose+scale W_span -> WsT[o][c], c = m*16+l ----------------
__global__ void k0a_transpose(const float* __restrict__ Wspan, float* __restrict__ WsT) {
    int idx = blockIdx.x * 256 + threadIdx.x;   // 0..16383 (float4 groups)
    int o  = idx >> 3;                          // 0..2047
    int c0 = (idx & 7) * 4;
    float v[4];
    #pragma unroll
    for (int q = 0; q < 4; ++q) {
        int c = c0 + q;
        int l = c & 15, m = c >> 4;
        v[q] = LOG2E * Wspan[l * (2 * H) + m * H + o];
    }
    *(float4*)&WsT[o * 32 + c0] = make_float4(v[0], v[1], v[2], v[3]);
}

// ------- K0b: cvec[c] = log2e*(bias_m . Wspan_m[l]) (+ log2e*b_span[l] for e-half) -----
__global__ void k0b_cvec(const float* __restrict__ b_start, const float* __restrict__ b_end,
                         const float* __restrict__ Wspan, const float* __restrict__ b_span,
                         float* __restrict__ cvec) {
    int c = blockIdx.x;                 // 0..31
    int l = c & 15, m = c >> 4;
    const float* bias = m ? b_end : b_start;
    int t = threadIdx.x;                // 64 threads = 1 wave
    float p = 0.f;
    for (int h = t; h < H; h += 64) p += bias[h] * Wspan[l * (2 * H) + m * H + h];
    #pragma unroll
    for (int off = 32; off; off >>= 1) p += __shfl_down(p, off);
    if (t == 0) cvec[c] = LOG2E * p + (m ? LOG2E * b_span[l] : 0.f);
}

// ---------------- K1a: partial A^T: p1[seg][k][l] = sum_{o in oc} WsT[o][c]*W[o][k] ----
__global__ __launch_bounds__(256) void k1a(const float* __restrict__ Wst,
                                           const float* __restrict__ Wen,
                                           const float* __restrict__ WsT,
                                           float* __restrict__ p1) {
    int blk = blockIdx.x;               // 256 = m(2) x kc(8) x oc(16)
    int m  = blk >> 7;
    int kc = (blk >> 4) & 7;
    int oc = blk & 15;
    const float* W = m ? Wen : Wst;
    int k = kc * 256 + threadIdx.x;
    float acc[16];
    #pragma unroll
    for (int i = 0; i < 16; ++i) acc[i] = 0.f;
    int o0 = oc * 128;
    for (int o = o0; o < o0 + 128; ++o) {
        float wv = W[(size_t)o * H + k];                 // coalesced over k
        const float* wsr = &WsT[o * 32 + m * 16];        // wave-uniform -> s_load
        #pragma unroll
        for (int l = 0; l < 16; ++l) acc[l] += wsr[l] * wv;
    }
    int seg = m * 16 + oc;              // 0..31
    float* dst = &p1[((size_t)seg * H + k) * 16];
    #pragma unroll
    for (int q = 0; q < 4; ++q)
        *(float4*)&dst[q * 4] = make_float4(acc[q*4], acc[q*4+1], acc[q*4+2], acc[q*4+3]);
}

// ---------------- K1b: AT[k][c] = sum_oc p1 ----------------
__global__ void k1b(const float* __restrict__ p1, float* __restrict__ AT) {
    int g = blockIdx.x * 256 + threadIdx.x;   // 16384 = 2048k x 8 cgroups
    int k  = g >> 3;
    int c0 = (g & 7) * 4;
    int m  = c0 >> 4;
    int l0 = c0 & 15;
    float sx = 0.f, sy = 0.f, sz = 0.f, sw = 0.f;
    #pragma unroll
    for (int oc = 0; oc < 16; ++oc) {
        const float* sp = &p1[(((size_t)(m * 16 + oc)) * H + k) * 16 + l0];
        float4 v = *(const float4*)sp;
        sx += v.x; sy += v.y; sz += v.z; sw += v.w;
    }
    *(float4*)&AT[(size_t)k * 32 + c0] = make_float4(sx, sy, sz, sw);
}

// ------- K2a: pp[ks][row][c] = sum_{k in ks-seg} x[row][k] * AT[k][c] ------------------
// Thread per row; AT rows wave-uniform -> SGPR operands; no LDS, no atomics.
__global__ __launch_bounds__(256) void k2a(const float* __restrict__ X,
                                           const float* __restrict__ AT,
                                           float* __restrict__ pp) {
    int blk = blockIdx.x;               // 256 = ks(8) x rg(32)
    int rg = blk & 31;
    int ks = blk >> 5;
    int t = threadIdx.x;
    int row = rg * 256 + t;
    const float* xp = X + (size_t)row * H + ks * 256;
    float acc[32];
    #pragma unroll
    for (int c = 0; c < 32; ++c) acc[c] = 0.f;
    for (int kk = 0; kk < 256; kk += 4) {
        float4 xv = *(const float4*)&xp[kk];
        const float* a = &AT[(size_t)(ks * 256 + kk) * 32];  // uniform -> s_load
        #pragma unroll
        for (int c = 0; c < 32; ++c) acc[c] += a[c] * xv.x;
        #pragma unroll
        for (int c = 0; c < 32; ++c) acc[c] += a[32 + c] * xv.y;
        #pragma unroll
        for (int c = 0; c < 32; ++c) acc[c] += a[64 + c] * xv.z;
        #pragma unroll
        for (int c = 0; c < 32; ++c) acc[c] += a[96 + c] * xv.w;
    }
    float* dst = &pp[((size_t)ks * NROWS + row) * 32];
    #pragma unroll
    for (int q = 0; q < 8; ++q)
        *(float4*)&dst[q * 4] = make_float4(acc[q*4], acc[q*4+1], acc[q*4+2], acc[q*4+3]);
}

// ---------------- K2b: proj[row][c] = sum_ks pp + cvec[c] ----------------
__global__ void k2b(const float* __restrict__ pp, const float* __restrict__ cvec,
                    float* __restrict__ proj) {
    int g = blockIdx.x * 256 + threadIdx.x;   // 65536 = 8192 rows x 8 cgroups
    int row = g >> 3;
    int c0  = (g & 7) * 4;
    float4 cv = *(const float4*)&cvec[c0];
    float sx = cv.x, sy = cv.y, sz = cv.z, sw = cv.w;
    #pragma unroll
    for (int ks = 0; ks < 8; ++ks) {
        float4 v = *(const float4*)&pp[((size_t)ks * NROWS + row) * 32 + c0];
        sx += v.x; sy += v.y; sz += v.z; sw += v.w;
    }
    *(float4*)&proj[(size_t)row * 32 + c0] = make_float4(sx, sy, sz, sw);
}

// ---------------- K3: pair softmax -> out (quad-per-pair, coalesced stores) ------------
// 4 lanes cooperate on one pair: lane handles quarter q = t&3 of the 16 logits.
// Store address = base + t*16 bytes -> every store instruction is 64 lanes x 16 B
// fully contiguous (1 KB), vs the old layout's 64-line scatter.
__global__ __launch_bounds__(256) void k3_pairs(const float* __restrict__ proj,
                                                float* __restrict__ out) {
    int blk = blockIdx.x;               // 8192 = b(8) x it(256) x jt(4)
    int b    = blk >> 10;
    int rest = blk & 1023;
    int it = rest >> 2;
    int jt = rest & 3;
    int i0 = it * 4;
    int j0 = jt * 256;
    if (j0 + 255 < i0) return;          // tile entirely below diagonal
    int t = threadIdx.x;
    int q = t & 3;                      // quarter of the 16-l vector
    int p = t >> 2;                     // pair-within-pass: 0..63

    // e-half quarters for the 4 j-subtiles (reused across the 4 i's)
    float4 ep[4];
    #pragma unroll
    for (int jj = 0; jj < 4; ++jj) {
        int j = j0 + jj * 64 + p;
        ep[jj] = *(const float4*)&proj[(size_t)(b * NSEQ + j) * 32 + 16 + q * 4];
    }
    size_t outB = (size_t)b * NPAIR;

    #pragma unroll
    for (int il = 0; il < 4; ++il) {
        int i = i0 + il;
        if (i > j0 + 255) continue;     // wave-uniform: no j in tile reaches diagonal
        // s-half quarter for this i: 4 distinct 16B addresses per wave -> L1 broadcast
        float4 s4 = *(const float4*)&proj[(size_t)(b * NSEQ + i) * 32 + q * 4];
        size_t rowBase = outB + (size_t)i * NSEQ - ((size_t)i * (i + 1)) / 2;  // + j
        #pragma unroll
        for (int jj = 0; jj < 4; ++jj) {
            int j = j0 + jj * 64 + p;
            float e0 = __builtin_amdgcn_exp2f(s4.x + ep[jj].x);   // pre-scaled by log2e
            float e1 = __builtin_amdgcn_exp2f(s4.y + ep[jj].y);
            float e2 = __builtin_amdgcn_exp2f(s4.z + ep[jj].z);
            float e3 = __builtin_amdgcn_exp2f(s4.w + ep[jj].w);
            float s = (e0 + e1) + (e2 + e3);
            s += __shfl_xor(s, 1);      // in-quad butterfly: full 16-wide denom
            s += __shfl_xor(s, 2);
            float r = __builtin_amdgcn_rcpf(s);
            if (i <= j) {
                float* po = out + (rowBase + (size_t)j) * 16 + q * 4;
                *(float4*)po = make_float4(e0 * r, e1 * r, e2 * r, e3 * r);
            }
        }
    }
}

extern "C" void kernel_launch(void* const* d_in, const int* in_sizes, int n_in,
                              void* d_out, int out_size, void* d_ws, size_t ws_size,
                              hipStream_t stream) {
    const float* x     = (const float*)d_in[0];
    const float* Wst   = (const float*)d_in[1];
    const float* bst   = (const float*)d_in[2];
    const float* Wen   = (const float*)d_in[3];
    const float* ben   = (const float*)d_in[4];
    const float* Wspan = (const float*)d_in[5];
    const float* bspan = (const float*)d_in[6];
    float* out = (float*)d_out;

    float* ws   = (float*)d_ws;
    float* WsT  = ws;                   //   65,536 floats
    float* cvec = ws + 65536;           //       64
    float* AT   = ws + 65600;           //   65,536
    float* p1   = ws + 131136;          // 1,048,576  (32 segs x 2048 x 16)
    float* pp   = ws + 1179712;         // 2,097,152  (8 ks x 8192 x 32)
    float* proj = ws + 3276864;         //   262,144
    // total 3,539,008 floats = 13.5 MB

    k0a_transpose<<<64, 256, 0, stream>>>(Wspan, WsT);
    k0b_cvec<<<32, 64, 0, stream>>>(bst, ben, Wspan, bspan, cvec);
    k1a<<<256, 256, 0, stream>>>(Wst, Wen, WsT, p1);
    k1b<<<64, 256, 0, stream>>>(p1, AT);
    k2a<<<256, 256, 0, stream>>>(x, AT, pp);
    k2b<<<256, 256, 0, stream>>>(pp, cvec, proj);
    k3_pairs<<<8192, 256, 0, stream>>>(proj, out);
}

// Round 2
// 429.381 us; speedup vs baseline: 1.1867x; 1.0246x over previous
//
#include <hip/hip_runtime.h>
#include <hip/hip_bf16.h>

// Problem: B=8, N=1024, H=2048, L=16
// out[b, tri(i,j), l] = softmax_l( s_proj[b,i,l] + e_proj[b,j,l] + b_span[l] )
// Collapse: A_s = Ws@W_start (16x2048), A_e = We@W_end; proj = x@[A_s;A_e]^T.
// All logits pre-scaled by log2(e) so softmax uses v_exp_f32 (exp2) directly.
// Streaming buffers (W, x, out) use nontemporal load/store to keep L2 for the
// intermediates (p1, pp, AT, proj) that are produced+consumed across kernels.

#define H 2048
#define NSEQ 1024
#define NROWS 8192            // B*N
#define NPAIR 524800          // 1024*1025/2
#define LOG2E 1.4426950408889634f

typedef float f32x4 __attribute__((ext_vector_type(4)));

// ---------------- K0a: transpose+scale W_span -> WsT[o][c], c = m*16+l ----------------
__global__ void k0a_transpose(const float* __restrict__ Wspan, float* __restrict__ WsT) {
    int idx = blockIdx.x * 256 + threadIdx.x;   // 0..16383 (float4 groups)
    int o  = idx >> 3;                          // 0..2047
    int c0 = (idx & 7) * 4;
    float v[4];
    #pragma unroll
    for (int q = 0; q < 4; ++q) {
        int c = c0 + q;
        int l = c & 15, m = c >> 4;
        v[q] = LOG2E * Wspan[l * (2 * H) + m * H + o];
    }
    *(float4*)&WsT[o * 32 + c0] = make_float4(v[0], v[1], v[2], v[3]);
}

// ------- K0b: cvec[c] = log2e*(bias_m . Wspan_m[l]) (+ log2e*b_span[l] for e-half) -----
__global__ void k0b_cvec(const float* __restrict__ b_start, const float* __restrict__ b_end,
                         const float* __restrict__ Wspan, const float* __restrict__ b_span,
                         float* __restrict__ cvec) {
    int c = blockIdx.x;                 // 0..31
    int l = c & 15, m = c >> 4;
    const float* bias = m ? b_end : b_start;
    int t = threadIdx.x;                // 64 threads = 1 wave
    float p = 0.f;
    for (int h = t; h < H; h += 64) p += bias[h] * Wspan[l * (2 * H) + m * H + h];
    #pragma unroll
    for (int off = 32; off; off >>= 1) p += __shfl_down(p, off);
    if (t == 0) cvec[c] = LOG2E * p + (m ? LOG2E * b_span[l] : 0.f);
}

// ---------------- K1a: partial A^T: p1[seg][k][l] = sum_{o in oc} WsT[o][c]*W[o][k] ----
__global__ __launch_bounds__(256) void k1a(const float* __restrict__ Wst,
                                           const float* __restrict__ Wen,
                                           const float* __restrict__ WsT,
                                           float* __restrict__ p1) {
    int blk = blockIdx.x;               // 256 = m(2) x kc(8) x oc(16)
    int m  = blk >> 7;
    int kc = (blk >> 4) & 7;
    int oc = blk & 15;
    const float* W = m ? Wen : Wst;
    int k = kc * 256 + threadIdx.x;
    float acc[16];
    #pragma unroll
    for (int i = 0; i < 16; ++i) acc[i] = 0.f;
    int o0 = oc * 128;
    for (int o = o0; o < o0 + 128; ++o) {
        float wv = __builtin_nontemporal_load(&W[(size_t)o * H + k]);  // one-shot stream
        const float* wsr = &WsT[o * 32 + m * 16];        // wave-uniform -> s_load
        #pragma unroll
        for (int l = 0; l < 16; ++l) acc[l] += wsr[l] * wv;
    }
    int seg = m * 16 + oc;              // 0..31
    float* dst = &p1[((size_t)seg * H + k) * 16];
    #pragma unroll
    for (int q = 0; q < 4; ++q)
        *(float4*)&dst[q * 4] = make_float4(acc[q*4], acc[q*4+1], acc[q*4+2], acc[q*4+3]);
}

// ---------------- K1b: AT[k][c] = sum_oc p1 ----------------
__global__ void k1b(const float* __restrict__ p1, float* __restrict__ AT) {
    int g = blockIdx.x * 256 + threadIdx.x;   // 16384 = 2048k x 8 cgroups
    int k  = g >> 3;
    int c0 = (g & 7) * 4;
    int m  = c0 >> 4;
    int l0 = c0 & 15;
    float sx = 0.f, sy = 0.f, sz = 0.f, sw = 0.f;
    #pragma unroll
    for (int oc = 0; oc < 16; ++oc) {
        const float* sp = &p1[(((size_t)(m * 16 + oc)) * H + k) * 16 + l0];
        float4 v = *(const float4*)sp;
        sx += v.x; sy += v.y; sz += v.z; sw += v.w;
    }
    *(float4*)&AT[(size_t)k * 32 + c0] = make_float4(sx, sy, sz, sw);
}

// ------- K2a: pp[ks][row][c] = sum_{k in ks-seg} x[row][k] * AT[k][c] ------------------
// Thread per row; AT rows wave-uniform -> SGPR operands; no LDS, no atomics.
__global__ __launch_bounds__(256) void k2a(const float* __restrict__ X,
                                           const float* __restrict__ AT,
                                           float* __restrict__ pp) {
    int blk = blockIdx.x;               // 256 = ks(8) x rg(32)
    int rg = blk & 31;
    int ks = blk >> 5;
    int t = threadIdx.x;
    int row = rg * 256 + t;
    const float* xp = X + (size_t)row * H + ks * 256;
    float acc[32];
    #pragma unroll
    for (int c = 0; c < 32; ++c) acc[c] = 0.f;
    for (int kk = 0; kk < 256; kk += 4) {
        f32x4 xv = __builtin_nontemporal_load((const f32x4*)&xp[kk]);  // one-shot stream
        const float* a = &AT[(size_t)(ks * 256 + kk) * 32];  // uniform -> s_load
        #pragma unroll
        for (int c = 0; c < 32; ++c) acc[c] += a[c] * xv.x;
        #pragma unroll
        for (int c = 0; c < 32; ++c) acc[c] += a[32 + c] * xv.y;
        #pragma unroll
        for (int c = 0; c < 32; ++c) acc[c] += a[64 + c] * xv.z;
        #pragma unroll
        for (int c = 0; c < 32; ++c) acc[c] += a[96 + c] * xv.w;
    }
    float* dst = &pp[((size_t)ks * NROWS + row) * 32];
    #pragma unroll
    for (int q = 0; q < 8; ++q)
        *(float4*)&dst[q * 4] = make_float4(acc[q*4], acc[q*4+1], acc[q*4+2], acc[q*4+3]);
}

// ---------------- K2b: proj[row][c] = sum_ks pp + cvec[c] ----------------
__global__ void k2b(const float* __restrict__ pp, const float* __restrict__ cvec,
                    float* __restrict__ proj) {
    int g = blockIdx.x * 256 + threadIdx.x;   // 65536 = 8192 rows x 8 cgroups
    int row = g >> 3;
    int c0  = (g & 7) * 4;
    float4 cv = *(const float4*)&cvec[c0];
    float sx = cv.x, sy = cv.y, sz = cv.z, sw = cv.w;
    #pragma unroll
    for (int ks = 0; ks < 8; ++ks) {
        float4 v = *(const float4*)&pp[((size_t)ks * NROWS + row) * 32 + c0];
        sx += v.x; sy += v.y; sz += v.z; sw += v.w;
    }
    *(float4*)&proj[(size_t)row * 32 + c0] = make_float4(sx, sy, sz, sw);
}

// ---------------- K3: pair softmax -> out (quad-per-pair, coalesced nt stores) ---------
// 4 lanes cooperate on one pair: lane handles quarter q = t&3 of the 16 logits.
// Store address = base + t*16 bytes -> 64 lanes x 16 B fully contiguous (1 KB).
// Grid enumerates only triangle-intersecting tiles: 640 per batch, 5120 total.
__global__ __launch_bounds__(256) void k3_pairs(const float* __restrict__ proj,
                                                float* __restrict__ out) {
    int blk = blockIdx.x;               // 5120 = b(8) x valid(640)
    int b = blk / 640;
    int v = blk - b * 640;
    int jt, it;
    if (v < 64)       { jt = 0; it = v; }
    else if (v < 192) { jt = 1; it = v - 64; }
    else if (v < 384) { jt = 2; it = v - 192; }
    else              { jt = 3; it = v - 384; }
    int i0 = it * 4;
    int j0 = jt * 256;
    int t = threadIdx.x;
    int q = t & 3;                      // quarter of the 16-l vector
    int p = t >> 2;                     // pair-within-pass: 0..63

    // e-half quarters for the 4 j-subtiles (reused across the 4 i's)
    float4 ep[4];
    #pragma unroll
    for (int jj = 0; jj < 4; ++jj) {
        int j = j0 + jj * 64 + p;
        ep[jj] = *(const float4*)&proj[(size_t)(b * NSEQ + j) * 32 + 16 + q * 4];
    }
    size_t outB = (size_t)b * NPAIR;

    #pragma unroll
    for (int il = 0; il < 4; ++il) {
        int i = i0 + il;
        // s-half quarter for this i: 4 distinct 16B addresses per wave -> L1 broadcast
        float4 s4 = *(const float4*)&proj[(size_t)(b * NSEQ + i) * 32 + q * 4];
        size_t rowBase = outB + (size_t)i * NSEQ - ((size_t)i * (i + 1)) / 2;  // + j
        #pragma unroll
        for (int jj = 0; jj < 4; ++jj) {
            int j = j0 + jj * 64 + p;
            float e0 = __builtin_amdgcn_exp2f(s4.x + ep[jj].x);   // pre-scaled by log2e
            float e1 = __builtin_amdgcn_exp2f(s4.y + ep[jj].y);
            float e2 = __builtin_amdgcn_exp2f(s4.z + ep[jj].z);
            float e3 = __builtin_amdgcn_exp2f(s4.w + ep[jj].w);
            float s = (e0 + e1) + (e2 + e3);
            s += __shfl_xor(s, 1);      // in-quad butterfly: full 16-wide denom
            s += __shfl_xor(s, 2);
            float r = __builtin_amdgcn_rcpf(s);
            if (i <= j) {
                float* po = out + (rowBase + (size_t)j) * 16 + q * 4;
                f32x4 res = { e0 * r, e1 * r, e2 * r, e3 * r };
                __builtin_nontemporal_store(res, (f32x4*)po);     // 268.7 MB one-shot
            }
        }
    }
}

extern "C" void kernel_launch(void* const* d_in, const int* in_sizes, int n_in,
                              void* d_out, int out_size, void* d_ws, size_t ws_size,
                              hipStream_t stream) {
    const float* x     = (const float*)d_in[0];
    const float* Wst   = (const float*)d_in[1];
    const float* bst   = (const float*)d_in[2];
    const float* Wen   = (const float*)d_in[3];
    const float* ben   = (const float*)d_in[4];
    const float* Wspan = (const float*)d_in[5];
    const float* bspan = (const float*)d_in[6];
    float* out = (float*)d_out;

    float* ws   = (float*)d_ws;
    float* WsT  = ws;                   //   65,536 floats
    float* cvec = ws + 65536;           //       64
    float* AT   = ws + 65600;           //   65,536
    float* p1   = ws + 131136;          // 1,048,576  (32 segs x 2048 x 16)
    float* pp   = ws + 1179712;         // 2,097,152  (8 ks x 8192 x 32)
    float* proj = ws + 3276864;         //   262,144
    // total 3,539,008 floats = 13.5 MB

    k0a_transpose<<<64, 256, 0, stream>>>(Wspan, WsT);
    k0b_cvec<<<32, 64, 0, stream>>>(bst, ben, Wspan, bspan, cvec);
    k1a<<<256, 256, 0, stream>>>(Wst, Wen, WsT, p1);
    k1b<<<64, 256, 0, stream>>>(p1, AT);
    k2a<<<256, 256, 0, stream>>>(x, AT, pp);
    k2b<<<256, 256, 0, stream>>>(pp, cvec, proj);
    k3_pairs<<<5120, 256, 0, stream>>>(proj, out);
}

// Round 3
// 428.837 us; speedup vs baseline: 1.1883x; 1.0013x over previous
//
#include <hip/hip_runtime.h>
#include <hip/hip_bf16.h>

// Problem: B=8, N=1024, H=2048, L=16
// out[b, tri(i,j), l] = softmax_l( s_proj[b,i,l] + e_proj[b,j,l] + b_span[l] )
// Collapse: A_s = Ws@W_start (16x2048), A_e = We@W_end; proj = x@[A_s;A_e]^T.
// Key algebraic trick: exp2(s_i + e_j) = exp2(s_i)*exp2(e_j). k2b stores
// EXPONENTIALS (eproj = exp2(proj + cvec)); k3's 67M-pair inner loop is then
// pure mul/add/rcp — no per-pair transcendentals (was 1.07G v_exp_f32).
// Streaming buffers (W, x, out) use nontemporal load/store to keep L2 for
// the intermediates.

#define H 2048
#define NSEQ 1024
#define NROWS 8192            // B*N
#define NPAIR 524800          // 1024*1025/2
#define LOG2E 1.4426950408889634f

typedef float f32x4 __attribute__((ext_vector_type(4)));

// ---------------- K0a: transpose+scale W_span -> WsT[o][c], c = m*16+l ----------------
__global__ void k0a_transpose(const float* __restrict__ Wspan, float* __restrict__ WsT) {
    int idx = blockIdx.x * 256 + threadIdx.x;   // 0..16383 (float4 groups)
    int o  = idx >> 3;                          // 0..2047
    int c0 = (idx & 7) * 4;
    float v[4];
    #pragma unroll
    for (int q = 0; q < 4; ++q) {
        int c = c0 + q;
        int l = c & 15, m = c >> 4;
        v[q] = LOG2E * Wspan[l * (2 * H) + m * H + o];
    }
    *(float4*)&WsT[o * 32 + c0] = make_float4(v[0], v[1], v[2], v[3]);
}

// ------- K0b: cvec[c] = log2e*(bias_m . Wspan_m[l]) (+ log2e*b_span[l] for e-half) -----
__global__ void k0b_cvec(const float* __restrict__ b_start, const float* __restrict__ b_end,
                         const float* __restrict__ Wspan, const float* __restrict__ b_span,
                         float* __restrict__ cvec) {
    int c = blockIdx.x;                 // 0..31
    int l = c & 15, m = c >> 4;
    const float* bias = m ? b_end : b_start;
    int t = threadIdx.x;                // 64 threads = 1 wave
    float p = 0.f;
    for (int h = t; h < H; h += 64) p += bias[h] * Wspan[l * (2 * H) + m * H + h];
    #pragma unroll
    for (int off = 32; off; off >>= 1) p += __shfl_down(p, off);
    if (t == 0) cvec[c] = LOG2E * p + (m ? LOG2E * b_span[l] : 0.f);
}

// ---------------- K1a: partial A^T: p1[seg][k][l] = sum_{o in oc} WsT[o][c]*W[o][k] ----
__global__ __launch_bounds__(256) void k1a(const float* __restrict__ Wst,
                                           const float* __restrict__ Wen,
                                           const float* __restrict__ WsT,
                                           float* __restrict__ p1) {
    int blk = blockIdx.x;               // 256 = m(2) x kc(8) x oc(16)
    int m  = blk >> 7;
    int kc = (blk >> 4) & 7;
    int oc = blk & 15;
    const float* W = m ? Wen : Wst;
    int k = kc * 256 + threadIdx.x;
    float acc[16];
    #pragma unroll
    for (int i = 0; i < 16; ++i) acc[i] = 0.f;
    int o0 = oc * 128;
    for (int o = o0; o < o0 + 128; ++o) {
        float wv = __builtin_nontemporal_load(&W[(size_t)o * H + k]);  // one-shot stream
        const float* wsr = &WsT[o * 32 + m * 16];        // wave-uniform -> s_load
        #pragma unroll
        for (int l = 0; l < 16; ++l) acc[l] += wsr[l] * wv;
    }
    int seg = m * 16 + oc;              // 0..31
    float* dst = &p1[((size_t)seg * H + k) * 16];
    #pragma unroll
    for (int q = 0; q < 4; ++q)
        *(float4*)&dst[q * 4] = make_float4(acc[q*4], acc[q*4+1], acc[q*4+2], acc[q*4+3]);
}

// ---------------- K1b: AT[k][c] = sum_oc p1 ----------------
__global__ void k1b(const float* __restrict__ p1, float* __restrict__ AT) {
    int g = blockIdx.x * 256 + threadIdx.x;   // 16384 = 2048k x 8 cgroups
    int k  = g >> 3;
    int c0 = (g & 7) * 4;
    int m  = c0 >> 4;
    int l0 = c0 & 15;
    float sx = 0.f, sy = 0.f, sz = 0.f, sw = 0.f;
    #pragma unroll
    for (int oc = 0; oc < 16; ++oc) {
        const float* sp = &p1[(((size_t)(m * 16 + oc)) * H + k) * 16 + l0];
        float4 v = *(const float4*)sp;
        sx += v.x; sy += v.y; sz += v.z; sw += v.w;
    }
    *(float4*)&AT[(size_t)k * 32 + c0] = make_float4(sx, sy, sz, sw);
}

// ------- K2a: pp[ks][row][c] = sum_{k in ks-seg} x[row][k] * AT[k][c] ------------------
// Thread per row; AT rows wave-uniform -> SGPR operands; no LDS, no atomics.
__global__ __launch_bounds__(256) void k2a(const float* __restrict__ X,
                                           const float* __restrict__ AT,
                                           float* __restrict__ pp) {
    int blk = blockIdx.x;               // 256 = ks(8) x rg(32)
    int rg = blk & 31;
    int ks = blk >> 5;
    int t = threadIdx.x;
    int row = rg * 256 + t;
    const float* xp = X + (size_t)row * H + ks * 256;
    float acc[32];
    #pragma unroll
    for (int c = 0; c < 32; ++c) acc[c] = 0.f;
    for (int kk = 0; kk < 256; kk += 4) {
        f32x4 xv = __builtin_nontemporal_load((const f32x4*)&xp[kk]);  // one-shot stream
        const float* a = &AT[(size_t)(ks * 256 + kk) * 32];  // uniform -> s_load
        #pragma unroll
        for (int c = 0; c < 32; ++c) acc[c] += a[c] * xv.x;
        #pragma unroll
        for (int c = 0; c < 32; ++c) acc[c] += a[32 + c] * xv.y;
        #pragma unroll
        for (int c = 0; c < 32; ++c) acc[c] += a[64 + c] * xv.z;
        #pragma unroll
        for (int c = 0; c < 32; ++c) acc[c] += a[96 + c] * xv.w;
    }
    float* dst = &pp[((size_t)ks * NROWS + row) * 32];
    #pragma unroll
    for (int q = 0; q < 8; ++q)
        *(float4*)&dst[q * 4] = make_float4(acc[q*4], acc[q*4+1], acc[q*4+2], acc[q*4+3]);
}

// -------- K2b: eproj[row][c] = exp2( sum_ks pp + cvec[c] ) -- EXPONENTIAL domain -------
__global__ void k2b(const float* __restrict__ pp, const float* __restrict__ cvec,
                    float* __restrict__ eproj) {
    int g = blockIdx.x * 256 + threadIdx.x;   // 65536 = 8192 rows x 8 cgroups
    int row = g >> 3;
    int c0  = (g & 7) * 4;
    float4 cv = *(const float4*)&cvec[c0];
    float sx = cv.x, sy = cv.y, sz = cv.z, sw = cv.w;
    #pragma unroll
    for (int ks = 0; ks < 8; ++ks) {
        float4 v = *(const float4*)&pp[((size_t)ks * NROWS + row) * 32 + c0];
        sx += v.x; sy += v.y; sz += v.z; sw += v.w;
    }
    *(float4*)&eproj[(size_t)row * 32 + c0] =
        make_float4(__builtin_amdgcn_exp2f(sx), __builtin_amdgcn_exp2f(sy),
                    __builtin_amdgcn_exp2f(sz), __builtin_amdgcn_exp2f(sw));
}

// ---------------- K3: pair softmax -> out (quad-per-pair, factored exp) ----------------
// exp2(s_i+e_j) = es_i * ee_j: inner loop is 8 mul + 5 add + 2 shfl + 1 rcp per
// lane-quarter — zero transcendentals. 4 lanes cooperate on one pair (q = t&3);
// stores are 64-lane x 16 B contiguous (1 KB), nontemporal (268.7 MB one-shot).
// Grid enumerates only triangle-intersecting tiles: 640 per batch, 5120 total.
__global__ __launch_bounds__(256) void k3_pairs(const float* __restrict__ eproj,
                                                float* __restrict__ out) {
    int blk = blockIdx.x;               // 5120 = b(8) x valid(640)
    int b = blk / 640;
    int v = blk - b * 640;
    int jt, it;
    if (v < 64)       { jt = 0; it = v; }
    else if (v < 192) { jt = 1; it = v - 64; }
    else if (v < 384) { jt = 2; it = v - 192; }
    else              { jt = 3; it = v - 384; }
    int i0 = it * 4;
    int j0 = jt * 256;
    int t = threadIdx.x;
    int q = t & 3;                      // quarter of the 16-l vector
    int p = t >> 2;                     // pair-within-pass: 0..63

    // e-half exp quarters for the 4 j-subtiles (reused across the 4 i's)
    float4 ee[4];
    #pragma unroll
    for (int jj = 0; jj < 4; ++jj) {
        int j = j0 + jj * 64 + p;
        ee[jj] = *(const float4*)&eproj[(size_t)(b * NSEQ + j) * 32 + 16 + q * 4];
    }
    size_t outB = (size_t)b * NPAIR;

    #pragma unroll
    for (int il = 0; il < 4; ++il) {
        int i = i0 + il;
        // s-half exp quarter for this i: 4 distinct 16B addrs per wave -> L1 broadcast
        float4 es = *(const float4*)&eproj[(size_t)(b * NSEQ + i) * 32 + q * 4];
        size_t rowBase = outB + (size_t)i * NSEQ - ((size_t)i * (i + 1)) / 2;  // + j
        #pragma unroll
        for (int jj = 0; jj < 4; ++jj) {
            int j = j0 + jj * 64 + p;
            float p0 = es.x * ee[jj].x;
            float p1 = es.y * ee[jj].y;
            float p2 = es.z * ee[jj].z;
            float p3 = es.w * ee[jj].w;
            float s = (p0 + p1) + (p2 + p3);
            s += __shfl_xor(s, 1);      // in-quad butterfly: full 16-wide denom
            s += __shfl_xor(s, 2);
            float r = __builtin_amdgcn_rcpf(s);
            if (i <= j) {
                float* po = out + (rowBase + (size_t)j) * 16 + q * 4;
                f32x4 res = { p0 * r, p1 * r, p2 * r, p3 * r };
                __builtin_nontemporal_store(res, (f32x4*)po);
            }
        }
    }
}

extern "C" void kernel_launch(void* const* d_in, const int* in_sizes, int n_in,
                              void* d_out, int out_size, void* d_ws, size_t ws_size,
                              hipStream_t stream) {
    const float* x     = (const float*)d_in[0];
    const float* Wst   = (const float*)d_in[1];
    const float* bst   = (const float*)d_in[2];
    const float* Wen   = (const float*)d_in[3];
    const float* ben   = (const float*)d_in[4];
    const float* Wspan = (const float*)d_in[5];
    const float* bspan = (const float*)d_in[6];
    float* out = (float*)d_out;

    float* ws    = (float*)d_ws;
    float* WsT   = ws;                   //   65,536 floats
    float* cvec  = ws + 65536;           //       64
    float* AT    = ws + 65600;           //   65,536
    float* p1    = ws + 131136;          // 1,048,576  (32 segs x 2048 x 16)
    float* pp    = ws + 1179712;         // 2,097,152  (8 ks x 8192 x 32)
    float* eproj = ws + 3276864;         //   262,144
    // total 3,539,008 floats = 13.5 MB

    k0a_transpose<<<64, 256, 0, stream>>>(Wspan, WsT);
    k0b_cvec<<<32, 64, 0, stream>>>(bst, ben, Wspan, bspan, cvec);
    k1a<<<256, 256, 0, stream>>>(Wst, Wen, WsT, p1);
    k1b<<<64, 256, 0, stream>>>(p1, AT);
    k2a<<<256, 256, 0, stream>>>(x, AT, pp);
    k2b<<<256, 256, 0, stream>>>(pp, cvec, eproj);
    k3_pairs<<<5120, 256, 0, stream>>>(eproj, out);
}